// Round 3
// baseline (364.799 us; speedup 1.0000x reference)
//
#include <hip/hip_runtime.h>

#define NTOK 1024
#define CDIM 1024
#define CRDIM 256
#define ENUM 8
#define IDIM 4096
#define WSTRIDE 4194304ull  // C*I elements per expert weight matrix
#define SBPAD 56            // fallback LDS row stride in ushorts

typedef __bf16 bf16x8 __attribute__((ext_vector_type(8)));
typedef float f32x4 __attribute__((ext_vector_type(4)));

typedef const unsigned int __attribute__((address_space(1))) gu32;
typedef unsigned int __attribute__((address_space(3))) lu32;

__device__ __forceinline__ void glds16(const unsigned short* g, unsigned short* l) {
  __builtin_amdgcn_global_load_lds((gu32*)g, (lu32*)l, 16, 0, 0);
}

__device__ __forceinline__ unsigned short f2bf(float f) {
  union { float f; unsigned int u; } v; v.f = f;
  unsigned int r = v.u + 0x7FFFu + ((v.u >> 16) & 1u);  // RNE
  return (unsigned short)(r >> 16);
}

// ---------------- init + cast x to bf16, zero out ----------------
__global__ __launch_bounds__(256) void init_cast_kernel(
    const float* __restrict__ x, unsigned short* __restrict__ xb,
    float* __restrict__ out) {
  int t = blockIdx.x * 256 + threadIdx.x;
  float4 v = reinterpret_cast<const float4*>(x)[t];
  ushort4 o;
  o.x = f2bf(v.x); o.y = f2bf(v.y); o.z = f2bf(v.z); o.w = f2bf(v.w);
  reinterpret_cast<ushort4*>(xb)[t] = o;
  float4 z; z.x = 0.f; z.y = 0.f; z.z = 0.f; z.w = 0.f;
  reinterpret_cast<float4*>(out)[t] = z;
}

// ---------------- router: gates + top-2 ----------------
#define RT 8
__global__ __launch_bounds__(256) void router_kernel(
    const float* __restrict__ x, const float* __restrict__ Wr1,
    const float* __restrict__ br1, const float* __restrict__ Wr2,
    const float* __restrict__ br2, int* __restrict__ ti,
    float* __restrict__ tw) {
  __shared__ float xs[RT][CDIM];
  __shared__ float hs[RT][CRDIM];
  __shared__ float lg[RT][ENUM];
  const int tid = threadIdx.x;
  const int tok0 = blockIdx.x * RT;
  for (int r = 0; r < RT; ++r) {
    float4 v = reinterpret_cast<const float4*>(x + (size_t)(tok0 + r) * CDIM)[tid];
    *reinterpret_cast<float4*>(&xs[r][tid * 4]) = v;
  }
  __syncthreads();
  float acc[RT];
#pragma unroll
  for (int r = 0; r < RT; ++r) acc[r] = 0.f;
  const int j = tid;
  for (int i = 0; i < CDIM; ++i) {
    float w = Wr1[(size_t)i * CRDIM + j];
#pragma unroll
    for (int r = 0; r < RT; ++r) acc[r] += xs[r][i] * w;
  }
  float b = br1[j];
#pragma unroll
  for (int r = 0; r < RT; ++r) hs[r][j] = fmaxf(acc[r] + b, 0.f);
  __syncthreads();
  if (tid < RT * ENUM) {
    int r = tid >> 3, e = tid & 7;
    float a = 0.f;
    for (int i = 0; i < CRDIM; ++i) a += hs[r][i] * Wr2[(size_t)i * ENUM + e];
    lg[r][e] = a + br2[e];
  }
  __syncthreads();
  if (tid < RT) {
    int r = tid;
    float m = lg[r][0];
#pragma unroll
    for (int e = 1; e < 8; ++e) m = fmaxf(m, lg[r][e]);
    float s = 0.f, g[8];
#pragma unroll
    for (int e = 0; e < 8; ++e) { g[e] = expf(lg[r][e] - m); s += g[e]; }
    float inv = 1.f / s;
    int i0 = 0; float g0 = -1.f;
#pragma unroll
    for (int e = 0; e < 8; ++e) { float ge = g[e] * inv; if (ge > g0) { g0 = ge; i0 = e; } }
    int i1 = 0; float g1 = -2.f;
#pragma unroll
    for (int e = 0; e < 8; ++e) { float ge = g[e] * inv; if (e != i0 && ge > g1) { g1 = ge; i1 = e; } }
    float w0 = 1.f / (1.f + expf((g1 - g0) * 0.5f));
    int n = tok0 + r;
    ti[2 * n] = i0; ti[2 * n + 1] = i1;
    tw[2 * n] = w0; tw[2 * n + 1] = 1.f - w0;
  }
}

// ---------------- per-expert token lists (stable order) ----------------
__global__ __launch_bounds__(1024) void build_lists_kernel(
    const int* __restrict__ ti, const float* __restrict__ tw,
    int* __restrict__ cnt, int* __restrict__ list, float* __restrict__ gw) {
  __shared__ int s[NTOK];
  const int e = blockIdx.x, n = threadIdx.x;
  int a = ti[2 * n], b = ti[2 * n + 1];
  float w = (a == e) ? tw[2 * n] : ((b == e) ? tw[2 * n + 1] : 0.f);
  int flag = (a == e || b == e) ? 1 : 0;
  s[n] = flag;
  __syncthreads();
  for (int off = 1; off < NTOK; off <<= 1) {
    int v = (n >= off) ? s[n - off] : 0;
    __syncthreads();
    s[n] += v;
    __syncthreads();
  }
  if (flag) { int pos = s[n] - 1; list[e * NTOK + pos] = n; gw[e * NTOK + pos] = w; }
  if (n == NTOK - 1) cnt[e] = s[n];
}

__global__ void offsets_kernel(const int* __restrict__ cnt, int* __restrict__ offs) {
  if (threadIdx.x == 0) {
    int o = 0;
    for (int e = 0; e < 8; ++e) { offs[e] = o; o += cnt[e]; }
    offs[8] = o;
  }
}

// ---------------- transpose + f32->bf16 convert: src [KD][ND] -> dst [ND][KD] ----
template <int KD, int ND>
__global__ __launch_bounds__(256) void transpose_cvt(
    const float* __restrict__ Wr, const float* __restrict__ Wsh,
    unsigned short* __restrict__ dst) {
  const int e = blockIdx.z;
  const float* src = (e < 8) ? (Wr + (size_t)e * WSTRIDE) : Wsh;
  unsigned short* dse = dst + (size_t)e * WSTRIDE;
  const int n0 = blockIdx.x * 128, k0 = blockIdx.y * 128;
  __shared__ __align__(16) unsigned short lt[128][136];  // [n][k], 272B rows
  const int tid = threadIdx.x;
  const int bn = tid >> 3, bk0 = tid & 7;
#pragma unroll
  for (int i = 0; i < 4; ++i) {
    const int bk = bk0 + 8 * i;
    const float* sp = src + (size_t)(k0 + 4 * bk) * ND + n0 + 4 * bn;
    float4 r0 = *reinterpret_cast<const float4*>(sp);
    float4 r1 = *reinterpret_cast<const float4*>(sp + ND);
    float4 r2 = *reinterpret_cast<const float4*>(sp + 2 * (size_t)ND);
    float4 r3 = *reinterpret_cast<const float4*>(sp + 3 * (size_t)ND);
    ushort4 c;
    c.x = f2bf(r0.x); c.y = f2bf(r1.x); c.z = f2bf(r2.x); c.w = f2bf(r3.x);
    *reinterpret_cast<ushort4*>(&lt[4 * bn + 0][4 * bk]) = c;
    c.x = f2bf(r0.y); c.y = f2bf(r1.y); c.z = f2bf(r2.y); c.w = f2bf(r3.y);
    *reinterpret_cast<ushort4*>(&lt[4 * bn + 1][4 * bk]) = c;
    c.x = f2bf(r0.z); c.y = f2bf(r1.z); c.z = f2bf(r2.z); c.w = f2bf(r3.z);
    *reinterpret_cast<ushort4*>(&lt[4 * bn + 2][4 * bk]) = c;
    c.x = f2bf(r0.w); c.y = f2bf(r1.w); c.z = f2bf(r2.w); c.w = f2bf(r3.w);
    *reinterpret_cast<ushort4*>(&lt[4 * bn + 3][4 * bk]) = c;
  }
  __syncthreads();
#pragma unroll
  for (int p = 0; p < 2; ++p) {
    const int n = (tid >> 2) + 64 * p;
    const int seg = (tid & 3) * 32;
    const uint4 d0 = *reinterpret_cast<const uint4*>(&lt[n][seg]);
    const uint4 d1 = *reinterpret_cast<const uint4*>(&lt[n][seg + 8]);
    const uint4 d2 = *reinterpret_cast<const uint4*>(&lt[n][seg + 16]);
    const uint4 d3 = *reinterpret_cast<const uint4*>(&lt[n][seg + 24]);
    unsigned short* o = dse + (size_t)(n0 + n) * KD + k0 + seg;
    reinterpret_cast<uint4*>(o)[0] = d0;
    reinterpret_cast<uint4*>(o)[1] = d1;
    reinterpret_cast<uint4*>(o)[2] = d2;
    reinterpret_cast<uint4*>(o)[3] = d3;
  }
}

// ---------------- fast GEMM path: bf16 A + transposed bf16 B, global_load_lds ----
// MODE 0: H = silu(Xg @ W1 + b1); MODE 1: out += gate*(H @ W2 + b2), split-K=4
template <int MODE>
__global__ __launch_bounds__(256) void moe_gemm_t(
    const unsigned short* __restrict__ Abase, const unsigned short* __restrict__ Bt,
    const float* __restrict__ br, const float* __restrict__ bsh,
    const int* __restrict__ cnt, const int* __restrict__ offs,
    const int* __restrict__ list, const float* __restrict__ gw,
    unsigned short* __restrict__ Hout, float* __restrict__ out) {
  constexpr int KD = (MODE == 0) ? CDIM : IDIM;
  constexpr int ND = (MODE == 0) ? IDIM : CDIM;
  constexpr int KCH = (MODE == 0) ? KD : (KD / 4);
  const int nt = blockIdx.x, mt = blockIdx.y;
  const int e = (MODE == 0) ? blockIdx.z : (blockIdx.z % 9);
  const int kc = (MODE == 0) ? 0 : (blockIdx.z / 9);
  const int me = (e < 8) ? cnt[e] : NTOK;
  const int row0 = mt * 128;
  if (row0 >= me) return;
  const int valid = min(128, me - row0);
  const int n0 = nt * 128;
  const unsigned short* Bsrc = Bt + (size_t)e * WSTRIDE;
  const float* bias = (e < 8) ? (br + (size_t)e * ND) : bsh;
  const int hbase = (e < 8) ? offs[e] : 2048;
  const int tid = threadIdx.x;
  const int lane = tid & 63, w = tid >> 6;

  __shared__ __align__(16) unsigned short sA[128 * 32];
  __shared__ __align__(16) unsigned short sB[128 * 32];
  __shared__ int sTok[128];
  __shared__ float sGate[128];

  if (MODE == 1 && e < 8 && tid < 128) {
    int ic = min(tid, valid - 1);
    sTok[tid] = list[e * NTOK + row0 + ic];
    sGate[tid] = (tid < valid) ? gw[e * NTOK + row0 + tid] : 0.f;
  }

  // staging geometry: wave w covers rows [16w,16w+16) and [64+16w, 64+16w+16)
  // LDS(row, slot) holds global k-chunk (slot ^ ((row>>1)&3))  [2-way-free swizzle]
  const int rl = lane >> 2, cs = lane & 3;
  const int ra0 = w * 16 + rl, ra1 = 64 + w * 16 + rl;
  const int qa0 = cs ^ ((ra0 >> 1) & 3), qa1 = cs ^ ((ra1 >> 1) & 3);
  const int kbeg = kc * KCH;
  size_t arow0, arow1;
  if (MODE == 0) {
    if (e < 8) {
      arow0 = (size_t)list[e * NTOK + row0 + min(ra0, valid - 1)];
      arow1 = (size_t)list[e * NTOK + row0 + min(ra1, valid - 1)];
    } else { arow0 = (size_t)(row0 + ra0); arow1 = (size_t)(row0 + ra1); }
  } else { arow0 = (size_t)(hbase + row0 + ra0); arow1 = (size_t)(hbase + row0 + ra1); }
  const unsigned short* srcA0 = Abase + arow0 * KD + kbeg + qa0 * 8;
  const unsigned short* srcA1 = Abase + arow1 * KD + kbeg + qa1 * 8;
  const unsigned short* srcB0 = Bsrc + (size_t)(n0 + ra0) * KD + kbeg + qa0 * 8;
  const unsigned short* srcB1 = Bsrc + (size_t)(n0 + ra1) * KD + kbeg + qa1 * 8;
  unsigned short* dA0 = sA + w * 16 * 32;
  unsigned short* dA1 = sA + (64 + w * 16) * 32;
  unsigned short* dB0 = sB + w * 16 * 32;
  unsigned short* dB1 = sB + (64 + w * 16) * 32;

  const int wr = (w >> 1) * 64, wc = (w & 1) * 64;
  const int lr = lane & 15, q = lane >> 4;
  int offA[4], offB[4];
#pragma unroll
  for (int m = 0; m < 4; ++m) { int R = wr + m * 16 + lr; offA[m] = R * 32 + (q ^ ((R >> 1) & 3)) * 8; }
#pragma unroll
  for (int n = 0; n < 4; ++n) { int R = wc + n * 16 + lr; offB[n] = R * 32 + (q ^ ((R >> 1) & 3)) * 8; }

  f32x4 acc[4][4];
#pragma unroll
  for (int m = 0; m < 4; ++m)
#pragma unroll
    for (int n = 0; n < 4; ++n) acc[m][n] = (f32x4)0.f;

  for (int k0 = 0; k0 < KCH; k0 += 32) {
    glds16(srcA0 + k0, dA0);
    glds16(srcA1 + k0, dA1);
    glds16(srcB0 + k0, dB0);
    glds16(srcB1 + k0, dB1);
    __syncthreads();  // vmcnt(0) drain + barrier: tile visible
    bf16x8 av[4], bv[4];
#pragma unroll
    for (int m = 0; m < 4; ++m) av[m] = *reinterpret_cast<const bf16x8*>(sA + offA[m]);
#pragma unroll
    for (int n = 0; n < 4; ++n) bv[n] = *reinterpret_cast<const bf16x8*>(sB + offB[n]);
#pragma unroll
    for (int m = 0; m < 4; ++m)
#pragma unroll
      for (int n = 0; n < 4; ++n)
        acc[m][n] = __builtin_amdgcn_mfma_f32_16x16x32_bf16(av[m], bv[n], acc[m][n], 0, 0, 0);
    __syncthreads();  // MFMA consumed tile; LDS reusable
  }

  const int rbase = wr + (q << 2);
#pragma unroll
  for (int n = 0; n < 4; ++n) {
    const int col = n0 + wc + n * 16 + lr;
    const float bval = (MODE == 0 || kc == 0) ? bias[col] : 0.f;
#pragma unroll
    for (int m = 0; m < 4; ++m) {
#pragma unroll
      for (int r = 0; r < 4; ++r) {
        const int i = rbase + m * 16 + r;
        if (i < valid) {
          float v = acc[m][n][r] + bval;
          if (MODE == 0) {
            float sv = v / (1.f + __expf(-v));
            Hout[(size_t)(hbase + row0 + i) * IDIM + col] = f2bf(sv);
          } else {
            if (e < 8)
              atomicAdd(&out[(size_t)sTok[i] * CDIM + col], sGate[i] * v);
            else
              atomicAdd(&out[(size_t)(row0 + i) * CDIM + col], v);
          }
        }
      }
    }
  }
}

// ---------------- fallback GEMM (round-2 path, used if ws too small) ----------
template <int MODE>
__global__ __launch_bounds__(256) void moe_gemm(
    const unsigned short* __restrict__ Abase, const float* __restrict__ Wr,
    const float* __restrict__ Wsh, const float* __restrict__ br,
    const float* __restrict__ bsh, const int* __restrict__ cnt,
    const int* __restrict__ offs, const int* __restrict__ list,
    const float* __restrict__ gw, unsigned short* __restrict__ Hout,
    float* __restrict__ out) {
  constexpr int KD = (MODE == 0) ? CDIM : IDIM;
  constexpr int ND = (MODE == 0) ? IDIM : CDIM;
  constexpr int KCH = (MODE == 0) ? KD : (KD / 4);
  const int nt = blockIdx.x, mt = blockIdx.y;
  const int e = (MODE == 0) ? blockIdx.z : (blockIdx.z % 9);
  const int kc = (MODE == 0) ? 0 : (blockIdx.z / 9);
  const int me = (e < 8) ? cnt[e] : NTOK;
  const int row0 = mt * 128;
  if (row0 >= me) return;
  const int valid = min(128, me - row0);
  const int n0 = nt * 128;
  const float* Bsrc = (e < 8) ? (Wr + (size_t)e * WSTRIDE) : Wsh;
  const float* bias = (e < 8) ? (br + (size_t)e * ND) : bsh;
  const int hbase = (e < 8) ? offs[e] : 2048;
  const int tid = threadIdx.x;

  __shared__ __align__(16) unsigned short sA[128][SBPAD];
  __shared__ __align__(16) unsigned short sB[128][SBPAD];
  __shared__ int rowSrc[128];
  __shared__ int sTok[128];
  __shared__ float sGate[128];

  if (tid < 128) {
    int i = tid, ic = min(i, valid - 1);
    if (MODE == 0) {
      rowSrc[i] = (e < 8) ? list[e * NTOK + row0 + ic] : (row0 + ic);
    } else {
      rowSrc[i] = hbase + row0 + i;
      if (e < 8) {
        sTok[i] = list[e * NTOK + row0 + ic];
        sGate[i] = (i < valid) ? gw[e * NTOK + row0 + i] : 0.f;
      }
    }
  }

  f32x4 acc[4][4];
#pragma unroll
  for (int m = 0; m < 4; ++m)
#pragma unroll
    for (int n = 0; n < 4; ++n) acc[m][n] = (f32x4)0.f;

  const int lane = tid & 63;
  const int wv = tid >> 6;
  const int wr = (wv >> 1) * 64, wc = (wv & 1) * 64;
  const int lr = lane & 15, lk = (lane >> 4) * 8;
  const int rowA = tid >> 2, kgA = (tid & 3) * 8;
  const int ncB = (tid & 63) * 2, kpB = tid >> 6;
  __syncthreads();

  const int kbeg = kc * KCH, kend = kbeg + KCH;
  uint4 pa0, pa1;
  float2 pb[8];

#define LOADTILE(K0)                                                            \
  {                                                                             \
    pa0 = *reinterpret_cast<const uint4*>(Abase + (size_t)rowSrc[rowA] * KD + (K0) + kgA);      \
    pa1 = *reinterpret_cast<const uint4*>(Abase + (size_t)rowSrc[rowA + 64] * KD + (K0) + kgA); \
    const float* Bp = Bsrc + (size_t)((K0) + kpB * 8) * ND + n0 + ncB;          \
    _Pragma("unroll") for (int j = 0; j < 8; ++j)                               \
        pb[j] = *reinterpret_cast<const float2*>(Bp + (size_t)j * ND);          \
  }

  LOADTILE(kbeg);
  for (int k0 = kbeg; k0 < kend; k0 += 32) {
    __syncthreads();
    *reinterpret_cast<uint4*>(&sA[rowA][kgA]) = pa0;
    *reinterpret_cast<uint4*>(&sA[rowA + 64][kgA]) = pa1;
    {
      bf16x8 q0, q1;
#pragma unroll
      for (int j = 0; j < 8; ++j) { q0[j] = (__bf16)pb[j].x; q1[j] = (__bf16)pb[j].y; }
      *reinterpret_cast<bf16x8*>(&sB[ncB][kpB * 8]) = q0;
      *reinterpret_cast<bf16x8*>(&sB[ncB + 1][kpB * 8]) = q1;
    }
    __syncthreads();
    if (k0 + 32 < kend) LOADTILE(k0 + 32);
    bf16x8 av[4], bv[4];
#pragma unroll
    for (int m = 0; m < 4; ++m)
      av[m] = *reinterpret_cast<const bf16x8*>(&sA[wr + m * 16 + lr][lk]);
#pragma unroll
    for (int n = 0; n < 4; ++n)
      bv[n] = *reinterpret_cast<const bf16x8*>(&sB[wc + n * 16 + lr][lk]);
#pragma unroll
    for (int m = 0; m < 4; ++m)
#pragma unroll
      for (int n = 0; n < 4; ++n)
        acc[m][n] = __builtin_amdgcn_mfma_f32_16x16x32_bf16(av[m], bv[n], acc[m][n], 0, 0, 0);
  }
#undef LOADTILE

  const int rbase = wr + ((lane >> 4) << 2);
#pragma unroll
  for (int n = 0; n < 4; ++n) {
    const int col = n0 + wc + n * 16 + lr;
    const float bval = (MODE == 0 || kc == 0) ? bias[col] : 0.f;
#pragma unroll
    for (int m = 0; m < 4; ++m) {
#pragma unroll
      for (int r = 0; r < 4; ++r) {
        const int i = rbase + m * 16 + r;
        if (i < valid) {
          float v = acc[m][n][r] + bval;
          if (MODE == 0) {
            float sv = v / (1.f + __expf(-v));
            Hout[(size_t)(hbase + row0 + i) * IDIM + col] = f2bf(sv);
          } else {
            if (e < 8)
              atomicAdd(&out[(size_t)sTok[i] * CDIM + col], sGate[i] * v);
            else
              atomicAdd(&out[(size_t)(row0 + i) * CDIM + col], v);
          }
        }
      }
    }
  }
}

extern "C" void kernel_launch(void* const* d_in, const int* in_sizes, int n_in,
                              void* d_out, int out_size, void* d_ws, size_t ws_size,
                              hipStream_t stream) {
  const float* x = (const float*)d_in[0];
  const float* Wr1 = (const float*)d_in[1];
  const float* br1 = (const float*)d_in[2];
  const float* Wr2 = (const float*)d_in[3];
  const float* br2 = (const float*)d_in[4];
  const float* Ws1 = (const float*)d_in[5];
  const float* bs1 = (const float*)d_in[6];
  const float* Ws2 = (const float*)d_in[7];
  const float* bs2 = (const float*)d_in[8];
  const float* We1 = (const float*)d_in[9];
  const float* be1 = (const float*)d_in[10];
  const float* We2 = (const float*)d_in[11];
  const float* be2 = (const float*)d_in[12];
  float* out = (float*)d_out;

  char* ws = (char*)d_ws;
  unsigned short* xb = (unsigned short*)(ws + 0);            // 2 MB
  int* ti = (int*)(ws + 2097152);
  float* tw = (float*)(ws + 2105344);
  int* cnt = (int*)(ws + 2113536);
  int* offs = (int*)(ws + 2113792);
  int* list = (int*)(ws + 2114048);
  float* gw = (float*)(ws + 2146816);
  unsigned short* H = (unsigned short*)(ws + 2179584);       // 24 MB (3072 x 4096 bf16)
  const bool big = ws_size >= 103ull * 1024 * 1024;
  const bool huge = ws_size >= 179ull * 1024 * 1024;
  unsigned short* W1T = (unsigned short*)(ws + 27345920ull);                  // 72 MB
  unsigned short* W2T = huge ? (unsigned short*)(ws + 102843904ull) : W1T;    // 72 MB

  init_cast_kernel<<<1024, 256, 0, stream>>>(x, xb, out);
  router_kernel<<<NTOK / RT, 256, 0, stream>>>(x, Wr1, br1, Wr2, br2, ti, tw);
  build_lists_kernel<<<8, 1024, 0, stream>>>(ti, tw, cnt, list, gw);
  offsets_kernel<<<1, 64, 0, stream>>>(cnt, offs);

  if (big) {
    transpose_cvt<CDIM, IDIM><<<dim3(32, 8, 9), 256, 0, stream>>>(We1, Ws1, W1T);
    if (huge) transpose_cvt<IDIM, CDIM><<<dim3(8, 32, 9), 256, 0, stream>>>(We2, Ws2, W2T);
    moe_gemm_t<0><<<dim3(32, 8, 9), 256, 0, stream>>>(xb, W1T, be1, bs1, cnt, offs, list, gw, H, out);
    if (!huge) transpose_cvt<IDIM, CDIM><<<dim3(8, 32, 9), 256, 0, stream>>>(We2, Ws2, W2T);
    moe_gemm_t<1><<<dim3(8, 8, 36), 256, 0, stream>>>(H, W2T, be2, bs2, cnt, offs, list, gw, nullptr, out);
  } else {
    moe_gemm<0><<<dim3(32, 8, 9), 256, 0, stream>>>(xb, We1, Ws1, be1, bs1, cnt, offs, list, gw, H, out);
    moe_gemm<1><<<dim3(8, 8, 36), 256, 0, stream>>>(H, We2, Ws2, be2, bs2, cnt, offs, list, gw, nullptr, out);
  }
}